// Round 13
// baseline (114.055 us; speedup 1.0000x reference)
//
#include <hip/hip_runtime.h>
#include <hip/hip_bf16.h>
#include <math.h>

typedef __bf16 bf16x8 __attribute__((ext_vector_type(8)));
typedef __bf16 bf16x2 __attribute__((ext_vector_type(2)));
typedef short  s16x2  __attribute__((ext_vector_type(2)));
typedef short  s16x4  __attribute__((ext_vector_type(4)));
typedef float  floatx16 __attribute__((ext_vector_type(16)));

// Workspace layout (bytes):
//   Kq    bf16 [2][8192][16]        offset 0        (512 KB)  scaled by sqrt(log2 e)
//   Vswz  bf16 [2][8192][32]        offset 524288   (1 MB)    32x32x8 B-frag swizzled
//   Opart f32  [2*8192][16][32]     offset 1572864  (33.5 MB) plain-store partials
//   Lpart f32  [2*8192][16]         offset 35127296 (1 MB)
#define KQ_ELEMS (2 * 8192 * 16)
#define OPART_OFF 1572864
#define SQRT_LOG2E 1.2011224087864498f
#define LSPLIT 4

// ---------------- Kernel A: projections ----------------
__global__ __launch_bounds__(256) void proj_kernel(
    const float* __restrict__ in, const float* __restrict__ W1,
    const float* __restrict__ b1, const float* __restrict__ W2,
    const float* __restrict__ b2,
    __hip_bfloat16* __restrict__ Kq, __hip_bfloat16* __restrict__ Vswz)
{
    __shared__ float Xs[32][32];
    __shared__ float W1s[16 * 32];
    __shared__ float W2s[32 * 32];
    const int t = threadIdx.x;
    const int bid = blockIdx.x;       // 0..511
    const int b = bid >> 8;
    const int hw = bid & 255;

    {
        int l = t >> 3, cs = (t & 7) * 4;
        float4 v = *(const float4*)(in + (((size_t)b * 32 + l) * 256 + hw) * 32 + cs);
        *(float4*)&Xs[l][cs] = v;
    }
    if (t < 128) *(float4*)&W1s[t * 4] = *(const float4*)(W1 + t * 4);
    *(float4*)&W2s[t * 4] = *(const float4*)(W2 + t * 4);
    __syncthreads();

    const int c = t & 31;
    const int g = t >> 5;             // 0..7

#pragma unroll
    for (int oo = 0; oo < 2; ++oo) {
        int o = g * 2 + oo;           // 0..15
        float acc = b1[o];
#pragma unroll
        for (int l = 0; l < 32; ++l) acc += W1s[o * 32 + l] * Xs[l][c];
        int k = c >> 1;
        int i = (c & 1) * 4096 + o * 256 + hw;
        Kq[((size_t)b * 8192 + i) * 16 + k] = __float2bfloat16(acc * SQRT_LOG2E);
    }
#pragma unroll
    for (int oo = 0; oo < 4; ++oo) {
        int o = g * 4 + oo;           // 0..31
        float acc = b2[o];
#pragma unroll
        for (int l = 0; l < 32; ++l) acc += W2s[o * 32 + l] * Xs[l][c];
        // position j = o*256 + hw, channel c; 32x32x8 B-frag swizzle:
        // flat = jt*1024 + gg*256 + h*128 + c*4 + idx
        int j = o * 256 + hw;
        int jt = j >> 5, rem = j & 31;
        int gg = rem >> 3, h = (rem >> 2) & 1, idx = rem & 3;
        Vswz[(size_t)b * 262144 + jt * 1024 + gg * 256 + h * 128 + c * 4 + idx] =
            __float2bfloat16(acc);
    }
}

// ---------------- Kernel B: flash attention, LDS-free, plain-store partials ----------------
// block = 256 thr (4 waves), each wave owns 32 i-rows. grid = 2 * 64 * 16 = 2048.
// NOTE: no min-waves arg in __launch_bounds__ (R7: forcing 8/EU -> VGPR 32 -> spill).
// NOTE: partials via plain streaming stores, NOT atomics — R5..R12 showed device-scope
// fp32 atomic RMW (cross-XCD coherent point) pins the kernel at ~44 us regardless of
// inner-loop shape; R4's store-based variant ran ~30 us with identical math.
__global__ __launch_bounds__(256) void flash_kernel(
    const __hip_bfloat16* __restrict__ Kq, const __hip_bfloat16* __restrict__ Vswz,
    float* __restrict__ Opart, float* __restrict__ Lpart)
{
    const int t = threadIdx.x;
    const int lane = t & 63;
    const int wv = t >> 6;            // 0..3
    const int m = lane & 31;
    const int h = lane >> 5;          // 0/1

    const int bid = blockIdx.x;
    const int s = bid & ((1 << LSPLIT) - 1);
    const int itile = (bid >> LSPLIT) & 63;
    const int b = bid >> (LSPLIT + 6);
    const int i0 = itile * 128 + wv * 32;
    const int niter = (8192 >> LSPLIT) >> 5;   // 16 tiles of 32 j
    const int jt0 = s * niter;

    const __hip_bfloat16* Kb = Kq + (size_t)b * 8192 * 16;
    const __hip_bfloat16* Vb = Vswz + (size_t)b * 262144 + h * 128 + m * 4;

    // Q B-frag (regs): B[k=8h+idx][n=m] = Kq[i0+m][8h+idx]
    const bf16x8 bq = *(const bf16x8*)(Kb + (size_t)(i0 + m) * 16 + h * 8);

    floatx16 oa = {}, ob = {};
    float2 l01 = {0.f, 0.f}, l23 = {0.f, 0.f};

#pragma unroll 4
    for (int it = 0; it < niter; ++it) {
        const int jt = jt0 + it;
        bf16x8 ak = *(const bf16x8*)(Kb + (size_t)(jt * 32 + m) * 16 + h * 8);
        s16x4 vf0 = *(const s16x4*)(Vb + (size_t)jt * 1024 + 0);
        s16x4 vf1 = *(const s16x4*)(Vb + (size_t)jt * 1024 + 256);
        s16x4 vf2 = *(const s16x4*)(Vb + (size_t)jt * 1024 + 512);
        s16x4 vf3 = *(const s16x4*)(Vb + (size_t)jt * 1024 + 768);

        // S^T(32j x 32i) = K(A) x Q(B), K=16 exact
        floatx16 sc = __builtin_amdgcn_mfma_f32_32x32x16_bf16(ak, bq, (floatx16){}, 0, 0, 0);

        // P = 2^S ; reg 4g+idx holds j_loc = 8g+4h+idx == 32x32x8 A-layout.
#pragma unroll
        for (int g = 0; g < 4; ++g) {
            float e0 = __builtin_amdgcn_exp2f(sc[4 * g + 0]);
            float e1 = __builtin_amdgcn_exp2f(sc[4 * g + 1]);
            float e2 = __builtin_amdgcn_exp2f(sc[4 * g + 2]);
            float e3 = __builtin_amdgcn_exp2f(sc[4 * g + 3]);
            l01.x += e0; l01.y += e1; l23.x += e2; l23.y += e3;
#if defined(__has_builtin) && __has_builtin(__builtin_amdgcn_cvt_pk_bf16_f32)
            bf16x2 plo = __builtin_amdgcn_cvt_pk_bf16_f32(e0, e1);
            bf16x2 phi = __builtin_amdgcn_cvt_pk_bf16_f32(e2, e3);
#else
            bf16x2 plo = {(__bf16)e0, (__bf16)e1};
            bf16x2 phi = {(__bf16)e2, (__bf16)e3};
#endif
            s16x2 lo = __builtin_bit_cast(s16x2, plo);
            s16x2 hi = __builtin_bit_cast(s16x2, phi);
            s16x4 pb = {lo[0], lo[1], hi[0], hi[1]};
            s16x4 vf = (g == 0) ? vf0 : (g == 1) ? vf1 : (g == 2) ? vf2 : vf3;
            if (g < 2)
                oa = __builtin_amdgcn_mfma_f32_32x32x8bf16_1k(pb, vf, oa, 0, 0, 0);
            else
                ob = __builtin_amdgcn_mfma_f32_32x32x8bf16_1k(pb, vf, ob, 0, 0, 0);
        }
    }

    oa = oa + ob;
    float l = (l01.x + l01.y) + (l23.x + l23.y);
    l += __shfl_xor(l, 32);

    // plain-store partials: Opart[(row<<LSPLIT)|s][c] (split-inner, coalesced 128B rows)
    // reg r -> row i_loc=(r&3)+8*(r>>2)+4h, col c=m
#pragma unroll
    for (int r = 0; r < 16; ++r) {
        int iloc = (r & 3) + 8 * (r >> 2) + 4 * h;
        size_t row = (size_t)b * 8192 + i0 + iloc;
        Opart[((row << LSPLIT) | s) * 32 + m] = oa[r];
    }
    if (h == 0)
        Lpart[(((size_t)b * 8192 + i0 + m) << LSPLIT) | s] = l;
}

// ---------------- Kernel C: combine partials + epilogue (float4 vectorized) ----------------
__global__ __launch_bounds__(256) void combine_kernel(
    const float* __restrict__ Opart, const float* __restrict__ Lpart,
    const float* __restrict__ in, const float* __restrict__ gamma,
    float* __restrict__ out)
{
    const int gid = blockIdx.x * 256 + threadIdx.x;   // 0..131071
    const int row = gid >> 3;                          // 0..16383
    const int c4 = (gid & 7) * 4;
    const float* op = Opart + (((size_t)row << LSPLIT)) * 32 + c4;
    const float* lp = Lpart + ((size_t)row << LSPLIT);
    float4 acc = make_float4(0.f, 0.f, 0.f, 0.f);
    float lsum = 0.f;
#pragma unroll
    for (int s = 0; s < (1 << LSPLIT); ++s) {
        float4 v = *(const float4*)(op + s * 32);
        acc.x += v.x; acc.y += v.y; acc.z += v.z; acc.w += v.w;
        lsum += lp[s];
    }
    const size_t base = (size_t)row * 32 + c4;
    float4 x = *(const float4*)(in + base);
    const float gl = gamma[0] / lsum;
    float4 r;
    r.x = acc.x * gl + x.x;
    r.y = acc.y * gl + x.y;
    r.z = acc.z * gl + x.z;
    r.w = acc.w * gl + x.w;
    *(float4*)(out + base) = r;
}

extern "C" void kernel_launch(void* const* d_in, const int* in_sizes, int n_in,
                              void* d_out, int out_size, void* d_ws, size_t ws_size,
                              hipStream_t stream) {
    const float* in = (const float*)d_in[0];
    const float* W1 = (const float*)d_in[1];
    const float* b1 = (const float*)d_in[2];
    const float* W2 = (const float*)d_in[3];
    const float* b2 = (const float*)d_in[4];
    const float* gamma = (const float*)d_in[5];
    float* out = (float*)d_out;

    __hip_bfloat16* Kq = (__hip_bfloat16*)d_ws;
    __hip_bfloat16* Vswz = Kq + KQ_ELEMS;
    float* Opart = (float*)((char*)d_ws + OPART_OFF);
    float* Lpart = Opart + ((size_t)16384 << LSPLIT) * 32;

    proj_kernel<<<512, 256, 0, stream>>>(in, W1, b1, W2, b2, Kq, Vswz);
    flash_kernel<<<2 * 64 * (1 << LSPLIT), 256, 0, stream>>>(Kq, Vswz, Opart, Lpart);
    combine_kernel<<<512, 256, 0, stream>>>(Opart, Lpart, in, gamma, out);
}

// Round 14
// 109.182 us; speedup vs baseline: 1.0446x; 1.0446x over previous
//
#include <hip/hip_runtime.h>
#include <hip/hip_bf16.h>
#include <math.h>

typedef __bf16 bf16x8 __attribute__((ext_vector_type(8)));
typedef __bf16 bf16x2 __attribute__((ext_vector_type(2)));
typedef short  s16x2  __attribute__((ext_vector_type(2)));
typedef short  s16x4  __attribute__((ext_vector_type(4)));
typedef float  floatx16 __attribute__((ext_vector_type(16)));

// Workspace layout (bytes):
//   Kq    bf16 [2][8192][16]        offset 0        (512 KB)  scaled by sqrt(log2 e)
//   Vswz  bf16 [2][8192][32]        offset 524288   (1 MB)    32x32x8 B-frag swizzled
//   Opart f32  [2*8192][8][32]      offset 1572864  (16.8 MB) plain-store partials
//   Lpart f32  [2*8192][8]          after Opart     (512 KB)
#define KQ_ELEMS (2 * 8192 * 16)
#define OPART_OFF 1572864
#define SQRT_LOG2E 1.2011224087864498f
#define LSPLIT 3

// ---------------- Kernel A: projections ----------------
__global__ __launch_bounds__(256) void proj_kernel(
    const float* __restrict__ in, const float* __restrict__ W1,
    const float* __restrict__ b1, const float* __restrict__ W2,
    const float* __restrict__ b2,
    __hip_bfloat16* __restrict__ Kq, __hip_bfloat16* __restrict__ Vswz)
{
    __shared__ float Xs[32][32];
    __shared__ float W1s[16 * 32];
    __shared__ float W2s[32 * 32];
    const int t = threadIdx.x;
    const int bid = blockIdx.x;       // 0..511
    const int b = bid >> 8;
    const int hw = bid & 255;

    {
        int l = t >> 3, cs = (t & 7) * 4;
        float4 v = *(const float4*)(in + (((size_t)b * 32 + l) * 256 + hw) * 32 + cs);
        *(float4*)&Xs[l][cs] = v;
    }
    if (t < 128) *(float4*)&W1s[t * 4] = *(const float4*)(W1 + t * 4);
    *(float4*)&W2s[t * 4] = *(const float4*)(W2 + t * 4);
    __syncthreads();

    const int c = t & 31;
    const int g = t >> 5;             // 0..7

#pragma unroll
    for (int oo = 0; oo < 2; ++oo) {
        int o = g * 2 + oo;           // 0..15
        float acc = b1[o];
#pragma unroll
        for (int l = 0; l < 32; ++l) acc += W1s[o * 32 + l] * Xs[l][c];
        int k = c >> 1;
        int i = (c & 1) * 4096 + o * 256 + hw;
        Kq[((size_t)b * 8192 + i) * 16 + k] = __float2bfloat16(acc * SQRT_LOG2E);
    }
#pragma unroll
    for (int oo = 0; oo < 4; ++oo) {
        int o = g * 4 + oo;           // 0..31
        float acc = b2[o];
#pragma unroll
        for (int l = 0; l < 32; ++l) acc += W2s[o * 32 + l] * Xs[l][c];
        // position j = o*256 + hw, channel c; 32x32x8 B-frag swizzle:
        // flat = jt*1024 + gg*256 + h*128 + c*4 + idx
        int j = o * 256 + hw;
        int jt = j >> 5, rem = j & 31;
        int gg = rem >> 3, h = (rem >> 2) & 1, idx = rem & 3;
        Vswz[(size_t)b * 262144 + jt * 1024 + gg * 256 + h * 128 + c * 4 + idx] =
            __float2bfloat16(acc);
    }
}

// ---------------- Kernel B: flash attention, LDS-free, plain-store partials ----------------
// block = 256 thr (4 waves), each wave owns 32 i-rows. grid = 2 * 64 * 8 = 1024.
// NOTE: no min-waves arg in __launch_bounds__ (R7: forcing 8/EU -> VGPR 32 -> spill).
// NOTE: partials via plain streaming stores, NOT atomics — R5..R12 showed device-scope
// fp32 atomic RMW (cross-XCD coherent point) pins the kernel at ~44 us regardless of
// inner-loop shape; R13's store-based variant broke that ceiling.
__global__ __launch_bounds__(256) void flash_kernel(
    const __hip_bfloat16* __restrict__ Kq, const __hip_bfloat16* __restrict__ Vswz,
    float* __restrict__ Opart, float* __restrict__ Lpart)
{
    const int t = threadIdx.x;
    const int lane = t & 63;
    const int wv = t >> 6;            // 0..3
    const int m = lane & 31;
    const int h = lane >> 5;          // 0/1

    const int bid = blockIdx.x;
    const int s = bid & ((1 << LSPLIT) - 1);
    const int itile = (bid >> LSPLIT) & 63;
    const int b = bid >> (LSPLIT + 6);
    const int i0 = itile * 128 + wv * 32;
    const int niter = (8192 >> LSPLIT) >> 5;   // 32 tiles of 32 j
    const int jt0 = s * niter;

    const __hip_bfloat16* Kb = Kq + (size_t)b * 8192 * 16;
    const __hip_bfloat16* Vb = Vswz + (size_t)b * 262144 + h * 128 + m * 4;

    // Q B-frag (regs): B[k=8h+idx][n=m] = Kq[i0+m][8h+idx]
    const bf16x8 bq = *(const bf16x8*)(Kb + (size_t)(i0 + m) * 16 + h * 8);

    floatx16 oa = {}, ob = {};
    float2 l01 = {0.f, 0.f}, l23 = {0.f, 0.f};

#pragma unroll 4
    for (int it = 0; it < niter; ++it) {
        const int jt = jt0 + it;
        bf16x8 ak = *(const bf16x8*)(Kb + (size_t)(jt * 32 + m) * 16 + h * 8);
        s16x4 vf0 = *(const s16x4*)(Vb + (size_t)jt * 1024 + 0);
        s16x4 vf1 = *(const s16x4*)(Vb + (size_t)jt * 1024 + 256);
        s16x4 vf2 = *(const s16x4*)(Vb + (size_t)jt * 1024 + 512);
        s16x4 vf3 = *(const s16x4*)(Vb + (size_t)jt * 1024 + 768);

        // S^T(32j x 32i) = K(A) x Q(B), K=16 exact
        floatx16 sc = __builtin_amdgcn_mfma_f32_32x32x16_bf16(ak, bq, (floatx16){}, 0, 0, 0);

        // P = 2^S ; reg 4g+idx holds j_loc = 8g+4h+idx == 32x32x8 A-layout.
#pragma unroll
        for (int g = 0; g < 4; ++g) {
            float e0 = __builtin_amdgcn_exp2f(sc[4 * g + 0]);
            float e1 = __builtin_amdgcn_exp2f(sc[4 * g + 1]);
            float e2 = __builtin_amdgcn_exp2f(sc[4 * g + 2]);
            float e3 = __builtin_amdgcn_exp2f(sc[4 * g + 3]);
            l01.x += e0; l01.y += e1; l23.x += e2; l23.y += e3;
#if defined(__has_builtin) && __has_builtin(__builtin_amdgcn_cvt_pk_bf16_f32)
            bf16x2 plo = __builtin_amdgcn_cvt_pk_bf16_f32(e0, e1);
            bf16x2 phi = __builtin_amdgcn_cvt_pk_bf16_f32(e2, e3);
#else
            bf16x2 plo = {(__bf16)e0, (__bf16)e1};
            bf16x2 phi = {(__bf16)e2, (__bf16)e3};
#endif
            s16x2 lo = __builtin_bit_cast(s16x2, plo);
            s16x2 hi = __builtin_bit_cast(s16x2, phi);
            s16x4 pb = {lo[0], lo[1], hi[0], hi[1]};
            s16x4 vf = (g == 0) ? vf0 : (g == 1) ? vf1 : (g == 2) ? vf2 : vf3;
            if (g < 2)
                oa = __builtin_amdgcn_mfma_f32_32x32x8bf16_1k(pb, vf, oa, 0, 0, 0);
            else
                ob = __builtin_amdgcn_mfma_f32_32x32x8bf16_1k(pb, vf, ob, 0, 0, 0);
        }
    }

    oa = oa + ob;
    float l = (l01.x + l01.y) + (l23.x + l23.y);
    l += __shfl_xor(l, 32);

    // plain-store partials: Opart[(row<<LSPLIT)|s][c] (split-inner, coalesced 128B rows)
    // reg r -> row i_loc=(r&3)+8*(r>>2)+4h, col c=m
#pragma unroll
    for (int r = 0; r < 16; ++r) {
        int iloc = (r & 3) + 8 * (r >> 2) + 4 * h;
        size_t row = (size_t)b * 8192 + i0 + iloc;
        Opart[((row << LSPLIT) | s) * 32 + m] = oa[r];
    }
    if (h == 0)
        Lpart[(((size_t)b * 8192 + i0 + m) << LSPLIT) | s] = l;
}

// ---------------- Kernel C: combine partials + epilogue (float4 vectorized) ----------------
__global__ __launch_bounds__(256) void combine_kernel(
    const float* __restrict__ Opart, const float* __restrict__ Lpart,
    const float* __restrict__ in, const float* __restrict__ gamma,
    float* __restrict__ out)
{
    const int gid = blockIdx.x * 256 + threadIdx.x;   // 0..131071
    const int row = gid >> 3;                          // 0..16383
    const int c4 = (gid & 7) * 4;
    const float* op = Opart + (((size_t)row << LSPLIT)) * 32 + c4;
    const float* lp = Lpart + ((size_t)row << LSPLIT);
    float4 acc = make_float4(0.f, 0.f, 0.f, 0.f);
    float lsum = 0.f;
#pragma unroll
    for (int s = 0; s < (1 << LSPLIT); ++s) {
        float4 v = *(const float4*)(op + s * 32);
        acc.x += v.x; acc.y += v.y; acc.z += v.z; acc.w += v.w;
        lsum += lp[s];
    }
    const size_t base = (size_t)row * 32 + c4;
    float4 x = *(const float4*)(in + base);
    const float gl = gamma[0] / lsum;
    float4 r;
    r.x = acc.x * gl + x.x;
    r.y = acc.y * gl + x.y;
    r.z = acc.z * gl + x.z;
    r.w = acc.w * gl + x.w;
    *(float4*)(out + base) = r;
}

extern "C" void kernel_launch(void* const* d_in, const int* in_sizes, int n_in,
                              void* d_out, int out_size, void* d_ws, size_t ws_size,
                              hipStream_t stream) {
    const float* in = (const float*)d_in[0];
    const float* W1 = (const float*)d_in[1];
    const float* b1 = (const float*)d_in[2];
    const float* W2 = (const float*)d_in[3];
    const float* b2 = (const float*)d_in[4];
    const float* gamma = (const float*)d_in[5];
    float* out = (float*)d_out;

    __hip_bfloat16* Kq = (__hip_bfloat16*)d_ws;
    __hip_bfloat16* Vswz = Kq + KQ_ELEMS;
    float* Opart = (float*)((char*)d_ws + OPART_OFF);
    float* Lpart = Opart + ((size_t)16384 << LSPLIT) * 32;

    proj_kernel<<<512, 256, 0, stream>>>(in, W1, b1, W2, b2, Kq, Vswz);
    flash_kernel<<<2 * 64 * (1 << LSPLIT), 256, 0, stream>>>(Kq, Vswz, Opart, Lpart);
    combine_kernel<<<512, 256, 0, stream>>>(Opart, Lpart, in, gamma, out);
}

// Round 15
// 107.179 us; speedup vs baseline: 1.0642x; 1.0187x over previous
//
#include <hip/hip_runtime.h>
#include <hip/hip_bf16.h>
#include <math.h>

typedef __bf16 bf16x8 __attribute__((ext_vector_type(8)));
typedef __bf16 bf16x2 __attribute__((ext_vector_type(2)));
typedef short  s16x2  __attribute__((ext_vector_type(2)));
typedef short  s16x4  __attribute__((ext_vector_type(4)));
typedef float  floatx16 __attribute__((ext_vector_type(16)));

// Workspace layout (bytes):
//   Kq    bf16 [2][8192][16]        offset 0        (512 KB)  scaled by sqrt(log2 e)
//   Vswz  bf16 [2][8192][32]        offset 524288   (1 MB)    32x32x8 B-frag swizzled
//   Opart bf16 [2*8192][8][32]      offset 1572864  (8.4 MB)  normalized ratios r_s = O_s/l_s
//   Lpart f32  [2*8192][8]          after Opart     (512 KB)
#define KQ_ELEMS (2 * 8192 * 16)
#define OPART_OFF 1572864
#define SQRT_LOG2E 1.2011224087864498f
#define LSPLIT 3

// ---------------- Kernel A: projections ----------------
__global__ __launch_bounds__(256) void proj_kernel(
    const float* __restrict__ in, const float* __restrict__ W1,
    const float* __restrict__ b1, const float* __restrict__ W2,
    const float* __restrict__ b2,
    __hip_bfloat16* __restrict__ Kq, __hip_bfloat16* __restrict__ Vswz)
{
    __shared__ float Xs[32][32];
    __shared__ float W1s[16 * 32];
    __shared__ float W2s[32 * 32];
    const int t = threadIdx.x;
    const int bid = blockIdx.x;       // 0..511
    const int b = bid >> 8;
    const int hw = bid & 255;

    {
        int l = t >> 3, cs = (t & 7) * 4;
        float4 v = *(const float4*)(in + (((size_t)b * 32 + l) * 256 + hw) * 32 + cs);
        *(float4*)&Xs[l][cs] = v;
    }
    if (t < 128) *(float4*)&W1s[t * 4] = *(const float4*)(W1 + t * 4);
    *(float4*)&W2s[t * 4] = *(const float4*)(W2 + t * 4);
    __syncthreads();

    const int c = t & 31;
    const int g = t >> 5;             // 0..7

#pragma unroll
    for (int oo = 0; oo < 2; ++oo) {
        int o = g * 2 + oo;           // 0..15
        float acc = b1[o];
#pragma unroll
        for (int l = 0; l < 32; ++l) acc += W1s[o * 32 + l] * Xs[l][c];
        int k = c >> 1;
        int i = (c & 1) * 4096 + o * 256 + hw;
        Kq[((size_t)b * 8192 + i) * 16 + k] = __float2bfloat16(acc * SQRT_LOG2E);
    }
#pragma unroll
    for (int oo = 0; oo < 4; ++oo) {
        int o = g * 4 + oo;           // 0..31
        float acc = b2[o];
#pragma unroll
        for (int l = 0; l < 32; ++l) acc += W2s[o * 32 + l] * Xs[l][c];
        // position j = o*256 + hw, channel c; 32x32x8 B-frag swizzle:
        // flat = jt*1024 + gg*256 + h*128 + c*4 + idx
        int j = o * 256 + hw;
        int jt = j >> 5, rem = j & 31;
        int gg = rem >> 3, h = (rem >> 2) & 1, idx = rem & 3;
        Vswz[(size_t)b * 262144 + jt * 1024 + gg * 256 + h * 128 + c * 4 + idx] =
            __float2bfloat16(acc);
    }
}

// ---------------- Kernel B: flash attention, LDS-free, bf16 normalized partials ----------------
// block = 256 thr (4 waves), each wave owns 32 i-rows. grid = 2 * 64 * 8 = 1024.
// NOTE: no min-waves arg in __launch_bounds__ (R7: forcing 8/EU -> VGPR 32 -> spill).
// NOTE: partials via plain streaming stores, NOT atomics — R5..R12 showed device-scope
// fp32 atomic RMW (cross-XCD coherent point) pins the kernel at ~44 us regardless of
// inner-loop shape; R13's store-based variant broke that ceiling.
__global__ __launch_bounds__(256) void flash_kernel(
    const __hip_bfloat16* __restrict__ Kq, const __hip_bfloat16* __restrict__ Vswz,
    __hip_bfloat16* __restrict__ Opart, float* __restrict__ Lpart)
{
    const int t = threadIdx.x;
    const int lane = t & 63;
    const int wv = t >> 6;            // 0..3
    const int m = lane & 31;
    const int h = lane >> 5;          // 0/1

    const int bid = blockIdx.x;
    const int s = bid & ((1 << LSPLIT) - 1);
    const int itile = (bid >> LSPLIT) & 63;
    const int b = bid >> (LSPLIT + 6);
    const int i0 = itile * 128 + wv * 32;
    const int niter = (8192 >> LSPLIT) >> 5;   // 32 tiles of 32 j
    const int jt0 = s * niter;

    const __hip_bfloat16* Kb = Kq + (size_t)b * 8192 * 16;
    const __hip_bfloat16* Vb = Vswz + (size_t)b * 262144 + h * 128 + m * 4;

    // Q B-frag (regs): B[k=8h+idx][n=m] = Kq[i0+m][8h+idx]
    const bf16x8 bq = *(const bf16x8*)(Kb + (size_t)(i0 + m) * 16 + h * 8);

    floatx16 oa = {}, ob = {};
    float2 l01 = {0.f, 0.f}, l23 = {0.f, 0.f};

#pragma unroll 4
    for (int it = 0; it < niter; ++it) {
        const int jt = jt0 + it;
        bf16x8 ak = *(const bf16x8*)(Kb + (size_t)(jt * 32 + m) * 16 + h * 8);
        s16x4 vf0 = *(const s16x4*)(Vb + (size_t)jt * 1024 + 0);
        s16x4 vf1 = *(const s16x4*)(Vb + (size_t)jt * 1024 + 256);
        s16x4 vf2 = *(const s16x4*)(Vb + (size_t)jt * 1024 + 512);
        s16x4 vf3 = *(const s16x4*)(Vb + (size_t)jt * 1024 + 768);

        // S^T(32j x 32i) = K(A) x Q(B), K=16 exact
        floatx16 sc = __builtin_amdgcn_mfma_f32_32x32x16_bf16(ak, bq, (floatx16){}, 0, 0, 0);

        // P = 2^S ; reg 4g+idx holds j_loc = 8g+4h+idx == 32x32x8 A-layout.
#pragma unroll
        for (int g = 0; g < 4; ++g) {
            float e0 = __builtin_amdgcn_exp2f(sc[4 * g + 0]);
            float e1 = __builtin_amdgcn_exp2f(sc[4 * g + 1]);
            float e2 = __builtin_amdgcn_exp2f(sc[4 * g + 2]);
            float e3 = __builtin_amdgcn_exp2f(sc[4 * g + 3]);
            l01.x += e0; l01.y += e1; l23.x += e2; l23.y += e3;
#if defined(__has_builtin) && __has_builtin(__builtin_amdgcn_cvt_pk_bf16_f32)
            bf16x2 plo = __builtin_amdgcn_cvt_pk_bf16_f32(e0, e1);
            bf16x2 phi = __builtin_amdgcn_cvt_pk_bf16_f32(e2, e3);
#else
            bf16x2 plo = {(__bf16)e0, (__bf16)e1};
            bf16x2 phi = {(__bf16)e2, (__bf16)e3};
#endif
            s16x2 lo = __builtin_bit_cast(s16x2, plo);
            s16x2 hi = __builtin_bit_cast(s16x2, phi);
            s16x4 pb = {lo[0], lo[1], hi[0], hi[1]};
            s16x4 vf = (g == 0) ? vf0 : (g == 1) ? vf1 : (g == 2) ? vf2 : vf3;
            if (g < 2)
                oa = __builtin_amdgcn_mfma_f32_32x32x8bf16_1k(pb, vf, oa, 0, 0, 0);
            else
                ob = __builtin_amdgcn_mfma_f32_32x32x8bf16_1k(pb, vf, ob, 0, 0, 0);
        }
    }

    oa = oa + ob;
    // full split-partial row-sum l_s for row i0+m (this lane's column)
    float l = (l01.x + l01.y) + (l23.x + l23.y);
    l += __shfl_xor(l, 32);
    const float rinv = __builtin_amdgcn_rcpf(l);

    // store normalized ratios r_s = O_s / l_s as bf16 (unit-scale, well-conditioned).
    // reg r -> row i_loc=(r&3)+8*(r>>2)+4h, col c=m ; l for row iloc lives in lane iloc
#pragma unroll
    for (int r = 0; r < 16; ++r) {
        int iloc = (r & 3) + 8 * (r >> 2) + 4 * h;
        float lr = __shfl(rinv, iloc);
        size_t row = (size_t)b * 8192 + i0 + iloc;
        Opart[((row << LSPLIT) | s) * 32 + m] = __float2bfloat16(oa[r] * lr);
    }
    if (h == 0)
        Lpart[(((size_t)b * 8192 + i0 + m) << LSPLIT) | s] = l;
}

// ---------------- Kernel C: weighted combine + epilogue ----------------
// out = (sum_s l_s * r_s) / (sum_s l_s) * gamma + in
__global__ __launch_bounds__(256) void combine_kernel(
    const unsigned short* __restrict__ Opart, const float* __restrict__ Lpart,
    const float* __restrict__ in, const float* __restrict__ gamma,
    float* __restrict__ out)
{
    const int gid = blockIdx.x * 256 + threadIdx.x;   // 0..131071
    const int row = gid >> 3;                          // 0..16383
    const int c4 = (gid & 7) * 4;
    const unsigned short* op = Opart + (((size_t)row << LSPLIT)) * 32 + c4;
    const float* lp = Lpart + ((size_t)row << LSPLIT);
    float4 acc = make_float4(0.f, 0.f, 0.f, 0.f);
    float lsum = 0.f;
#pragma unroll
    for (int s = 0; s < (1 << LSPLIT); ++s) {
        ushort4 u = *(const ushort4*)(op + s * 32);
        float ls = lp[s];
        acc.x += ls * __uint_as_float((unsigned)u.x << 16);
        acc.y += ls * __uint_as_float((unsigned)u.y << 16);
        acc.z += ls * __uint_as_float((unsigned)u.z << 16);
        acc.w += ls * __uint_as_float((unsigned)u.w << 16);
        lsum += ls;
    }
    const size_t base = (size_t)row * 32 + c4;
    float4 x = *(const float4*)(in + base);
    const float gl = gamma[0] / lsum;
    float4 r;
    r.x = acc.x * gl + x.x;
    r.y = acc.y * gl + x.y;
    r.z = acc.z * gl + x.z;
    r.w = acc.w * gl + x.w;
    *(float4*)(out + base) = r;
}

extern "C" void kernel_launch(void* const* d_in, const int* in_sizes, int n_in,
                              void* d_out, int out_size, void* d_ws, size_t ws_size,
                              hipStream_t stream) {
    const float* in = (const float*)d_in[0];
    const float* W1 = (const float*)d_in[1];
    const float* b1 = (const float*)d_in[2];
    const float* W2 = (const float*)d_in[3];
    const float* b2 = (const float*)d_in[4];
    const float* gamma = (const float*)d_in[5];
    float* out = (float*)d_out;

    __hip_bfloat16* Kq = (__hip_bfloat16*)d_ws;
    __hip_bfloat16* Vswz = Kq + KQ_ELEMS;
    __hip_bfloat16* Opart = (__hip_bfloat16*)((char*)d_ws + OPART_OFF);
    float* Lpart = (float*)(Opart + ((size_t)16384 << LSPLIT) * 32);

    proj_kernel<<<512, 256, 0, stream>>>(in, W1, b1, W2, b2, Kq, Vswz);
    flash_kernel<<<2 * 64 * (1 << LSPLIT), 256, 0, stream>>>(Kq, Vswz, Opart, Lpart);
    combine_kernel<<<512, 256, 0, stream>>>((const unsigned short*)Opart, Lpart, in, gamma, out);
}